// Round 9
// baseline (206.310 us; speedup 1.0000x reference)
//
#include <hip/hip_runtime.h>
#include <math.h>

#define NUM 576
#define BSTR 50
#define CTH 512
// dynamic LDS: band (576*50) + CTH-float dummy sink
#define CHOL_LDS_BYTES ((NUM * BSTR + CTH) * sizeof(float))

__device__ __forceinline__ float leakyf(float v) { return v > 0.f ? v : 0.01f * v; }
__device__ __forceinline__ float sigmoidf(float v) { return 1.f / (1.f + __expf(-v)); }
__device__ __forceinline__ float rdlane(float v, int l) {
  return __uint_as_float(__builtin_amdgcn_readlane(__float_as_uint(v), l));
}

// ---------------------------------------------------------------------------
// conv1 + SE fused. Halo-padded LDS staging (26x26 per channel, zero halo)
// kills all per-tap boundary cndmasks.
// ---------------------------------------------------------------------------
__global__ __launch_bounds__(576) void conv1se_kernel(
    const float* __restrict__ x,
    const float* __restrict__ wa, const float* __restrict__ ba,
    const float* __restrict__ wg, const float* __restrict__ bg,
    const float* __restrict__ sw1, const float* __restrict__ sb1,
    const float* __restrict__ sw2, const float* __restrict__ sb2,
    float* __restrict__ outa, float* __restrict__ outg,
    float* __restrict__ sev, double* __restrict__ acc)
{
  __shared__ float sx[16 * 676];
  __shared__ float pooled[64];
  __shared__ float hid[32];
  const int co = blockIdx.x, n = blockIdx.y;
  const int tid = threadIdx.x;

  if (co == 64) {
    if (tid < 2) acc[n * 2 + tid] = 0.0;
    if (tid < 64) {
      const float4* xp4 = (const float4*)(x + (size_t)(n * 64 + tid) * 576);
      float s = 0.f;
      for (int p = 0; p < 144; ++p) {
        float4 v = xp4[p];
        s += v.x + v.y + v.z + v.w;
      }
      pooled[tid] = s * (1.f / 576.f);
    }
    __syncthreads();
    if (tid < 32) {
      float h = sb1[tid];
      for (int c = 0; c < 64; ++c) h += pooled[c] * sw1[tid * 64 + c];
      hid[tid] = leakyf(h);
    }
    __syncthreads();
    if (tid < 16) {
      float v = sb2[tid];
      for (int j = 0; j < 32; ++j) v += hid[j] * sw2[tid * 32 + j];
      sev[n * 16 + tid] = sigmoidf(v);
    }
    return;
  }

  const int py = tid / 24, px = tid - py * 24;
  const int hb0 = py * 26 + px;   // top-left tap: (py+dy-1+1)*26 + (px+dx-1+1)
  for (int i = tid; i < 16 * 676; i += 576) sx[i] = 0.f;
  float acc_a = ba[co];
  float acc_g = bg[co];
  for (int c0 = 0; c0 < 64; c0 += 16) {
    __syncthreads();
#pragma unroll
    for (int q = 0; q < 4; ++q) {
      const int p = tid + q * 576;          // float4 index over (16ch,144)
      const int k = p / 144;
      const int r = p - k * 144;
      const int pix = r * 4;
      const int ppy = pix / 24, ppx = pix - ppy * 24;
      const float4 v = *(const float4*)&x[(size_t)(n * 64 + c0) * 576 + p * 4];
      float* d = &sx[k * 676 + (ppy + 1) * 26 + ppx + 1];
      d[0] = v.x; d[1] = v.y; d[2] = v.z; d[3] = v.w;
    }
    __syncthreads();
#pragma unroll 4
    for (int k = 0; k < 16; ++k) {
      const float* wpa = wa + (co * 64 + c0 + k) * 9;
      const float* wpg = wg + (co * 64 + c0 + k) * 9;
      const float* sp = &sx[k * 676 + hb0];
#pragma unroll
      for (int dy = 0; dy < 3; ++dy)
#pragma unroll
        for (int dx = 0; dx < 3; ++dx) {
          const float v = sp[dy * 26 + dx];
          acc_a += v * wpa[dy * 3 + dx];
          acc_g += v * wpg[dy * 3 + dx];
        }
    }
  }
  const int o = (n * 64 + co) * 576 + tid;
  outa[o] = leakyf(acc_a);
  outg[o] = leakyf(acc_g);
}

// ---------------------------------------------------------------------------
// conv2: second 3x3 conv per branch (halo-padded staging).
// ---------------------------------------------------------------------------
__global__ __launch_bounds__(576) void conv2_kernel(
    const float* __restrict__ t1a, const float* __restrict__ t1g,
    const float* __restrict__ wa, const float* __restrict__ ba,
    const float* __restrict__ wg, const float* __restrict__ bg,
    float* __restrict__ att, float* __restrict__ grd)
{
  __shared__ float sx[16 * 676];
  const int co = blockIdx.x, n = blockIdx.y, br = blockIdx.z;
  const float* src = br ? t1g : t1a;
  const float* wp0 = br ? wg : wa;
  const float bias = br ? bg[co] : ba[co];
  float* dst = br ? grd : att;
  const int tid = threadIdx.x;
  const int py = tid / 24, px = tid - py * 24;
  const int hb0 = py * 26 + px;
  for (int i = tid; i < 16 * 676; i += 576) sx[i] = 0.f;
  float acc = bias;
  for (int c0 = 0; c0 < 64; c0 += 16) {
    __syncthreads();
#pragma unroll
    for (int q = 0; q < 4; ++q) {
      const int p = tid + q * 576;
      const int k = p / 144;
      const int r = p - k * 144;
      const int pix = r * 4;
      const int ppy = pix / 24, ppx = pix - ppy * 24;
      const float4 v = *(const float4*)&src[(size_t)(n * 64 + c0) * 576 + p * 4];
      float* d = &sx[k * 676 + (ppy + 1) * 26 + ppx + 1];
      d[0] = v.x; d[1] = v.y; d[2] = v.z; d[3] = v.w;
    }
    __syncthreads();
#pragma unroll 4
    for (int k = 0; k < 16; ++k) {
      const float* wp = wp0 + (co * 64 + c0 + k) * 9;
      const float* sp = &sx[k * 676 + hb0];
#pragma unroll
      for (int dy = 0; dy < 3; ++dy)
#pragma unroll
        for (int dx = 0; dx < 3; ++dx)
          acc += sp[dy * 26 + dx] * wp[dy * 3 + dx];
    }
  }
  if (br == 0) acc = sigmoidf(acc);
  dst[(n * 64 + co) * 576 + tid] = acc;
}

// ---------------------------------------------------------------------------
// back-substitution helpers (register double-buffered L/rd/tail prefetch)
// ---------------------------------------------------------------------------
#define BS_LOAD(ip, L, rr, tl)                                                \
  {                                                                           \
    _Pragma("unroll")                                                         \
    for (int a = 0; a < 8; ++a)                                               \
      _Pragma("unroll")                                                       \
      for (int bb = a + 1; bb < 8; ++bb)                                      \
        L[a][bb] = S[((ip) - a) * BSTR + (bb - a)];                           \
    _Pragma("unroll")                                                         \
    for (int k = 0; k < 8; ++k) rr[k] = RD_s[(ip) - k];                       \
    _Pragma("unroll")                                                         \
    for (int k = 0; k < 8; ++k) {                                             \
      const int d = 8 + t - k;                                                \
      tl[k] = (d <= 48) ? S[((ip) - k) * BSTR + d] : 0.f;                     \
    }                                                                         \
  }

#define BS_STEP(i, L, rr, tl, ipre, Lp, rrp, tlp)                             \
  {                                                                           \
    asm volatile("s_waitcnt lgkmcnt(0)" ::: "memory");                        \
    float zz[8];                                                              \
    _Pragma("unroll")                                                         \
    for (int k = 0; k < 8; ++k) zz[k] = RHS_s[(i) - k];                       \
    const int rb = (i) - 8 - t;                                               \
    const bool bok = rb >= 0;                                                 \
    const float zbv = RHS_s[bok ? rb : 0];                                    \
    if ((ipre) >= 7) BS_LOAD(ipre, Lp, rrp, tlp);                             \
    float xx[8];                                                              \
    xx[0] = zz[0] * rr[0];                                                    \
    _Pragma("unroll")                                                         \
    for (int k = 1; k < 8; ++k) {                                             \
      float a2 = zz[k];                                                       \
      _Pragma("unroll")                                                       \
      for (int m = 0; m < 8; ++m)                                             \
        if (m < k) a2 -= L[m][k] * xx[m];                                     \
      xx[k] = a2 * rr[k];                                                     \
    }                                                                         \
    float at = 0.f;                                                           \
    _Pragma("unroll")                                                         \
    for (int k = 0; k < 8; ++k) at += tl[k] * xx[k];                          \
    float* rp = bok ? &RHS_s[rb] : &DUMW[t];                                  \
    *rp = zbv - at;                                                           \
    float xv = xx[0];                                                         \
    _Pragma("unroll")                                                         \
    for (int k = 1; k < 8; ++k) xv = (t == k) ? xx[k] : xv;                   \
    if (t < 8) XS_s[(i) - t] = xv;                                            \
  }

// ---------------------------------------------------------------------------
// Fused banded Cholesky solver. 512 threads (8 waves) per system b = n*16+g.
// Software-pipelined rank-8 supersteps:
//   Phase1: wave 0 runs the serial in-register 8-col micro-Cholesky (scale j)
//           CONCURRENTLY with waves 1-7 running the 210 NON-critical 2x2
//           tiles of update(j-8) (disjoint band columns; CP double-buffered).
//   Phase2: all waves run the 90 CRITICAL tiles (r2 in [8,15]) of update(j) —
//           exactly the elements scale(j+8) will read.
// Back substitution: 72 rank-8 steps with register-prefetched L blocks.
// ---------------------------------------------------------------------------
__global__ __launch_bounds__(CTH, 1) void chol_kernel(
    const float* __restrict__ att, const float* __restrict__ grd,
    float* __restrict__ sol, double* __restrict__ acc)
{
  extern __shared__ float S[];          // [28800] band + [CTH] dummy sink
  __shared__ float RHS_s[NUM];
  __shared__ float RD_s[NUM];
  __shared__ float XS_s[NUM];
  __shared__ __align__(16) float CP[2][8][64];  // double-buffered panel
  __shared__ float DUMW[64];
  __shared__ double RW[16];
  const int b = blockIdx.x, tid = threadIdx.x;
  const int n = b >> 4, g = b & 15;
  const float* ac = att + (size_t)(n * 64 + g * 4) * 576;
  const float* gc = grd + (size_t)(n * 64 + g * 4) * 576;

  // --- critical tile decode (90 tiles): W <= min(U,3)
  int r1C, r2C;
  const bool okC = tid < 90;
  {
    const int idx = okC ? tid : 0;
    int U, W;
    if (idx < 6) {
      U = (idx == 0) ? 0 : (idx < 3) ? 1 : 2;
      W = idx - U * (U + 1) / 2;
    } else {
      U = 3 + (idx - 6) / 4;
      W = (idx - 6) & 3;
    }
    r1C = 8 + 2 * U; r2C = 8 + 2 * W;
  }
  // --- non-critical tile decode (210 tiles): U>=4, 4<=W<=U
  int r1N, r2N;
  const bool okN = (tid >= 64) && (tid < 64 + 210);
  {
    const int idx = okN ? (tid - 64) : 0;
    int k = (int)((sqrtf(8.f * (float)idx + 1.f) - 1.f) * 0.5f);
    while (k * (k + 1) / 2 > idx) --k;
    while ((k + 1) * (k + 2) / 2 <= idx) ++k;
    const int w = idx - k * (k + 1) / 2;
    r1N = 8 + 2 * (k + 4); r2N = 8 + 2 * (w + 4);
  }

  // --- zero band
  for (int i = tid; i < NUM * BSTR; i += CTH) S[i] = 0.f;
  __syncthreads();

  // --- assemble band + rhs (verified math), seed rd[0]
  for (int i = tid; i < NUM; i += CTH) {
    float diag = 1e-12f, rv = 0.f;
    float od1 = 0.f, od2 = 0.f, od24 = 0.f, od48 = 0.f;
    if (((i + 1) % 24 != 0) && (i + 1 < NUM)) {
      float a0 = ac[0 * 576 + i]; float s = a0 * a0;
      diag += s; rv += s * gc[0 * 576 + i];
    }
    if (i - 1 >= 0 && (i % 24 != 0)) {
      float a0 = ac[0 * 576 + (i - 1)]; float s = a0 * a0;
      diag += s; rv -= s * gc[0 * 576 + (i - 1)]; od1 = -s;
    }
    if (i + 24 < NUM) {
      float a1 = ac[1 * 576 + i]; float s = a1 * a1;
      diag += s; rv += s * gc[1 * 576 + i];
    }
    if (i - 24 >= 0) {
      float a1 = ac[1 * 576 + (i - 24)]; float s = a1 * a1;
      diag += s; rv -= s * gc[1 * 576 + (i - 24)]; od24 = -s;
    }
    if (((i + 2) % 24 != 0) && (i + 2 < NUM)) {
      float a2 = ac[2 * 576 + i]; float s = a2 * a2;
      diag += s; rv += s * gc[2 * 576 + i];
    }
    if (i - 2 >= 0 && (i % 24 != 0)) {
      float a2 = ac[2 * 576 + (i - 2)]; float s = a2 * a2;
      diag += s; rv -= s * gc[2 * 576 + (i - 2)]; od2 = -s;
    }
    if (i + 48 < NUM) {
      float a3 = ac[3 * 576 + i]; float s = a3 * a3;
      diag += s; rv += s * gc[3 * 576 + i];
    }
    if (i - 48 >= 0) {
      float a3 = ac[3 * 576 + (i - 48)]; float s = a3 * a3;
      diag += s; rv -= s * gc[3 * 576 + (i - 48)]; od48 = -s;
    }
    if (i == NUM - 1) {
#pragma unroll
      for (int t = 0; t < 4; ++t) {
        float a = ac[t * 576 + (NUM - 1)]; float s = a * a;
        diag += s; rv += s * gc[t * 576 + (NUM - 1)];
      }
    }
    S[i * BSTR + 0] = diag;
    S[i * BSTR + 1] = od1;
    S[i * BSTR + 2] = od2;
    S[i * BSTR + 24] = od24;
    S[i * BSTR + 48] = od48;
    RHS_s[i] = rv;
    if (i == 0) RD_s[0] = rsqrtf(diag);
  }
  __syncthreads();

  // --- factorization: 72 pipelined rank-8 supersteps
  for (int j = 0; j < NUM; j += 8) {
    const int p = (j >> 3) & 1;
    // ==== Phase 1: wave0 scale(j)  ||  waves1-7 non-critical update(j-8)
    if (tid < 64) {
      const int t = tid;
      const int row = j + t;
      const bool rok = row < NUM;
      float v[8];
#pragma unroll
      for (int c = 0; c < 8; ++c) {
        const bool okc = rok && (t >= c) && (t - c <= 48);
        const int addr = okc ? (row * BSTR + (t - c)) : (NUM * BSTR + t);
        float vv = S[addr];
        v[c] = okc ? vv : 0.f;
      }
      float zb[8];
#pragma unroll
      for (int k = 0; k < 8; ++k) zb[k] = RHS_s[j + k];
      float z = RHS_s[rok ? row : j];
      z = rok ? z : 0.f;
      const float rd0 = RD_s[j];
      float rdv[8], y[8], lp[8][8];
#pragma unroll
      for (int k = 0; k < 8; ++k) {
        if (k == 0) {
          rdv[0] = rd0;
        } else {
          const float dk = rdlane(v[k], k);
          rdv[k] = rsqrtf(dk);
        }
        v[k] *= rdv[k];
#pragma unroll
        for (int m = k + 1; m < 8; ++m) {
          lp[m][k] = rdlane(v[k], m);
          v[m] -= v[k] * lp[m][k];
        }
      }
      y[0] = zb[0] * rdv[0];
#pragma unroll
      for (int k = 1; k < 8; ++k) {
        float a = zb[k];
#pragma unroll
        for (int m = 0; m < 8; ++m)
          if (m < k) a -= lp[k][m] * y[m];
        y[k] = a * rdv[k];
      }
      float zn = z;
#pragma unroll
      for (int c = 0; c < 8; ++c) zn -= v[c] * y[c];
#pragma unroll
      for (int c = 0; c < 8; ++c) {
        const bool okc = rok && (t > c) && (t - c <= 48);
        float* bp = okc ? &S[row * BSTR + (t - c)] : &S[NUM * BSTR + t];
        *bp = v[c];
        CP[p][c][t] = okc ? v[c] : 0.f;
      }
      if (t < 8) {
        float yv = y[0], rv = rdv[0];
#pragma unroll
        for (int k = 1; k < 8; ++k) {
          yv = (t == k) ? y[k] : yv;
          rv = (t == k) ? rdv[k] : rv;
        }
        RHS_s[row] = yv;
        RD_s[row] = rv;
      } else {
        float* rp = rok ? &RHS_s[row] : &DUMW[t & 63];
        *rp = zn;
      }
    } else {
      const int jp = j - 8;
      if (jp >= 0) {
        const int Rp = (NUM - 1) - jp;
        const bool a0 = okN && (r1N <= Rp);
        const bool a1 = okN && (r1N + 1 <= Rp);
        float2 cr[8], cc[8];
#pragma unroll
        for (int c = 0; c < 8; ++c) {
          cr[c] = *(const float2*)&CP[p ^ 1][c][r1N];
          cc[c] = *(const float2*)&CP[p ^ 1][c][r2N];
        }
        float s00 = 0.f, s01 = 0.f, s10 = 0.f, s11 = 0.f;
#pragma unroll
        for (int c = 0; c < 8; ++c) {
          s00 += cr[c].x * cc[c].x; s01 += cr[c].x * cc[c].y;
          s10 += cr[c].y * cc[c].x; s11 += cr[c].y * cc[c].y;
        }
        const int p00 = jp * BSTR + 51 * r1N - r2N;
        float* q00 = a0 ? &S[p00] : &S[NUM * BSTR + tid];
        float* q01 = a0 ? &S[p00 - 1] : &S[NUM * BSTR + tid];
        float* q10 = a1 ? &S[p00 + 51] : &S[NUM * BSTR + tid];
        float* q11 = a1 ? &S[p00 + 50] : &S[NUM * BSTR + tid];
        const float t00 = *q00 - s00, t01 = *q01 - s01;
        const float t10 = *q10 - s10, t11 = *q11 - s11;
        *q00 = t00; *q01 = t01; *q10 = t10; *q11 = t11;
      }
    }
    __syncthreads();
    // ==== Phase 2: all waves, critical tiles of update(j)
    {
      const int R = (NUM - 1) - j;
      const bool a0 = okC && (r1C <= R);
      const bool a1 = okC && (r1C + 1 <= R);
      float2 cr[8], cc[8];
#pragma unroll
      for (int c = 0; c < 8; ++c) {
        cr[c] = *(const float2*)&CP[p][c][r1C];
        cc[c] = *(const float2*)&CP[p][c][r2C];
      }
      float s00 = 0.f, s01 = 0.f, s10 = 0.f, s11 = 0.f;
#pragma unroll
      for (int c = 0; c < 8; ++c) {
        s00 += cr[c].x * cc[c].x; s01 += cr[c].x * cc[c].y;
        s10 += cr[c].y * cc[c].x; s11 += cr[c].y * cc[c].y;
      }
      const int p00 = j * BSTR + 51 * r1C - r2C;
      float* q00 = a0 ? &S[p00] : &S[NUM * BSTR + tid];
      float* q01 = a0 ? &S[p00 - 1] : &S[NUM * BSTR + tid];
      float* q10 = a1 ? &S[p00 + 51] : &S[NUM * BSTR + tid];
      float* q11 = a1 ? &S[p00 + 50] : &S[NUM * BSTR + tid];
      const float t00 = *q00 - s00, t01 = *q01 - s01;
      const float t10 = *q10 - s10, t11 = *q11 - s11;
      *q00 = t00; *q01 = t01; *q10 = t10; *q11 = t11;
      if (tid == 0 && a0)                  // tile (8,8): d_{j+8} final
        RD_s[j + 8] = rsqrtf(t00);
    }
    __syncthreads();
  }

  // --- back substitution: 72 rank-8 steps, single wave, reg-prefetched L
  if (tid < 64) {
    const int t = tid;
    float LA[8][8], LB[8][8], rrA[8], rrB[8], tlA[8], tlB[8];
    BS_LOAD(NUM - 1, LA, rrA, tlA);
    for (int i = NUM - 1; i >= 15; i -= 16) {
      BS_STEP(i, LA, rrA, tlA, i - 8, LB, rrB, tlB);
      BS_STEP(i - 8, LB, rrB, tlB, i - 16, LA, rrA, tlA);
    }
  }
  __syncthreads();

  // --- write solution + accumulate GroupNorm stats (double)
  double ls = 0.0, ls2 = 0.0;
  for (int i = tid; i < NUM; i += CTH) {
    const float xv = XS_s[i];
    sol[(size_t)b * NUM + i] = xv;
    ls += (double)xv;
    ls2 += (double)xv * (double)xv;
  }
#pragma unroll
  for (int off = 32; off > 0; off >>= 1) {
    ls += __shfl_down(ls, off);
    ls2 += __shfl_down(ls2, off);
  }
  if ((tid & 63) == 0) {
    RW[(tid >> 6) * 2] = ls;
    RW[(tid >> 6) * 2 + 1] = ls2;
  }
  __syncthreads();
  if (tid == 0) {
    double s = 0.0, s2 = 0.0;
#pragma unroll
    for (int wv = 0; wv < 8; ++wv) { s += RW[wv * 2]; s2 += RW[wv * 2 + 1]; }
    atomicAdd(&acc[n * 2], s);
    atomicAdd(&acc[n * 2 + 1], s2);
  }
}

// ---------------------------------------------------------------------------
// post conv fused with GroupNorm-apply + SE scale (halo-padded staging).
// ---------------------------------------------------------------------------
__global__ __launch_bounds__(576) void postgn_kernel(
    const float* __restrict__ sol, const double* __restrict__ acc,
    const float* __restrict__ sev,
    const float* __restrict__ gnw, const float* __restrict__ gnb,
    const float* __restrict__ w, const float* __restrict__ bias,
    float* __restrict__ out)
{
  __shared__ float sy[16 * 676];
  const int co = blockIdx.x, n = blockIdx.y, tid = threadIdx.x;
  const double mu_d = acc[n * 2] * (1.0 / 9216.0);
  const double var_d = acc[n * 2 + 1] * (1.0 / 9216.0) - mu_d * mu_d;
  const float rstd = (float)(1.0 / sqrt(var_d + 1e-5));
  const float muf = (float)mu_d;
  for (int i = tid; i < 16 * 676; i += 576) sy[i] = 0.f;
  __syncthreads();
#pragma unroll
  for (int q = 0; q < 4; ++q) {
    const int p = tid + q * 576;
    const int k = p / 144;
    const int r = p - k * 144;
    const int pix = r * 4;
    const int ppy = pix / 24, ppx = pix - ppy * 24;
    const float sv = sev[n * 16 + k];
    const float gw = gnw[k] * rstd;
    const float A = gw * sv;
    const float B = (gnb[k] - muf * gw) * sv;
    const float4 v = *(const float4*)&sol[(size_t)n * 9216 + p * 4];
    float* d = &sy[k * 676 + (ppy + 1) * 26 + ppx + 1];
    d[0] = v.x * A + B; d[1] = v.y * A + B;
    d[2] = v.z * A + B; d[3] = v.w * A + B;
  }
  __syncthreads();
  const int py = tid / 24, px = tid - py * 24;
  const int hb0 = py * 26 + px;
  float a = bias[co];
#pragma unroll 4
  for (int k = 0; k < 16; ++k) {
    const float* wp = w + (co * 16 + k) * 9;
    const float* sp = &sy[k * 676 + hb0];
#pragma unroll
    for (int dy = 0; dy < 3; ++dy)
#pragma unroll
      for (int dx = 0; dx < 3; ++dx)
        a += sp[dy * 26 + dx] * wp[dy * 3 + dx];
  }
  out[(size_t)(n * 128 + co) * 576 + tid] = a;
}

// ---------------------------------------------------------------------------
extern "C" void kernel_launch(void* const* d_in, const int* in_sizes, int n_in,
                              void* d_out, int out_size, void* d_ws, size_t ws_size,
                              hipStream_t stream) {
  const float* x       = (const float*)d_in[0];
  const float* grad_w1 = (const float*)d_in[2];
  const float* grad_b1 = (const float*)d_in[3];
  const float* grad_w2 = (const float*)d_in[4];
  const float* grad_b2 = (const float*)d_in[5];
  const float* att_w1  = (const float*)d_in[6];
  const float* att_b1  = (const float*)d_in[7];
  const float* att_w2  = (const float*)d_in[8];
  const float* att_b2  = (const float*)d_in[9];
  const float* se_w1   = (const float*)d_in[10];
  const float* se_b1   = (const float*)d_in[11];
  const float* se_w2   = (const float*)d_in[12];
  const float* se_b2   = (const float*)d_in[13];
  const float* gn_w    = (const float*)d_in[14];
  const float* gn_b    = (const float*)d_in[15];
  const float* post_w  = (const float*)d_in[16];
  const float* post_b  = (const float*)d_in[17];
  float* out = (float*)d_out;

  float* ws  = (float*)d_ws;
  float* t1a = ws;              // 147456
  float* t1g = t1a + 147456;    // 147456
  float* att = t1g + 147456;    // 147456
  float* grd = att + 147456;    // 147456
  float* sev = grd + 147456;    // 64
  float* sol = sev + 64;        // 36864
  double* acc = (double*)(sol + 36864);  // 8 doubles

  (void)hipFuncSetAttribute((const void*)chol_kernel,
                            hipFuncAttributeMaxDynamicSharedMemorySize,
                            (int)CHOL_LDS_BYTES);

  conv1se_kernel<<<dim3(65, 4), 576, 0, stream>>>(
      x, att_w1, att_b1, grad_w1, grad_b1,
      se_w1, se_b1, se_w2, se_b2, t1a, t1g, sev, acc);
  conv2_kernel<<<dim3(64, 4, 2), 576, 0, stream>>>(t1a, t1g, att_w2, att_b2,
                                                   grad_w2, grad_b2, att, grd);
  chol_kernel<<<64, CTH, CHOL_LDS_BYTES, stream>>>(att, grd, sol, acc);
  postgn_kernel<<<dim3(128, 4), 576, 0, stream>>>(sol, acc, sev, gn_w, gn_b,
                                                  post_w, post_b, out);
}